// Round 1
// baseline (1134.554 us; speedup 1.0000x reference)
//
#include <hip/hip_runtime.h>
#include <math.h>

#define NN 10000
#define NE 50000
#define BG 256
#define NNF 11
#define NT 12

typedef unsigned int u32;

__device__ __forceinline__ float sigm(float x){ return 1.0f/(1.0f+__expf(-x)); }
__device__ __forceinline__ u32 f2bf(float f){
  u32 u = __float_as_uint(f);
  return (u + 0x7fffu + ((u>>16)&1u)) >> 16;   // RNE
}
__device__ __forceinline__ float bf2f(u32 s){ return __uint_as_float(s<<16); }

// h[n,j] = j<11 ? x[n,j] : 0
__global__ void k_h_init(const float* __restrict__ x, float* __restrict__ h){
  int tid = blockIdx.x*256 + threadIdx.x;
  if (tid >= NN*64) return;
  int n = tid >> 6, j = tid & 63;
  h[tid] = (j < NNF) ? x[n*NNF + j] : 0.0f;
}

// generic transpose: in [R][C] -> out [C][R]
__global__ void k_T(const float* __restrict__ in, float* __restrict__ out, int R, int C){
  int tid = blockIdx.x*256 + threadIdx.x;
  if (tid >= R*C) return;
  int i = tid / C, j = tid - i*C;
  out[j*R + i] = in[i*C + j];
}

// Qt[hh*4096 + k*64 + o] = w1c[(hh*64+o)*64 + k]   (fp32, 1MB, L2-resident)
__global__ void k_qt(const float* __restrict__ w1c, float* __restrict__ Qt){
  int tid = blockIdx.x*256 + threadIdx.x;
  int hh = tid >> 12; int ko = tid & 4095; int k = ko >> 6; int o = ko & 63;
  Qt[tid] = w1c[(hh*64 + o)*64 + k];
}

// edge MLP: e1 = relu(relu(ea@w1a^T+b1a)@w1b^T+b1b), stored bf16
__global__ __launch_bounds__(256) void k_e1(const float* __restrict__ ea, const float* __restrict__ w1a,
                     const float* __restrict__ b1a, const float* __restrict__ w1bT,
                     const float* __restrict__ b1b, unsigned short* __restrict__ e1b){
  __shared__ float sw[64*64];
  __shared__ float sh1[4][64];
  int t = threadIdx.x;
  #pragma unroll
  for (int c = 0; c < 16; ++c) sw[c*256 + t] = w1bT[c*256 + t];
  int w = t >> 6, lane = t & 63;
  int e = blockIdx.x*4 + w;
  float h1 = 0.f;
  if (e < NE) {
    float a0 = ea[e*4+0], a1 = ea[e*4+1], a2 = ea[e*4+2], a3 = ea[e*4+3];
    h1 = b1a[lane] + a0*w1a[lane*4+0] + a1*w1a[lane*4+1] + a2*w1a[lane*4+2] + a3*w1a[lane*4+3];
    h1 = fmaxf(h1, 0.f);
  }
  sh1[w][lane] = h1;
  __syncthreads();
  if (e < NE) {
    float acc = b1b[lane];
    #pragma unroll 8
    for (int i = 0; i < 64; ++i) acc = fmaf(sh1[w][i], sw[i*64 + lane], acc);
    e1b[e*64 + lane] = (unsigned short)f2bf(fmaxf(acc, 0.f));
  }
}

// hb[n,o] = sum_h h[n,h]*b1c[h*64+o]
__global__ void k_hb(const float* __restrict__ h, const float* __restrict__ b1c, float* __restrict__ hb){
  int tid = blockIdx.x*256 + threadIdx.x;
  int n = tid >> 6, o = tid & 63;
  const float* hr = h + n*64;
  float acc = 0.f;
  #pragma unroll 8
  for (int i = 0; i < 64; ++i) acc = fmaf(hr[i], b1c[i*64 + o], acc);
  hb[tid] = acc;
}

// P[n, ko] = sum_h h[n,h] * Qt[h, ko]  -> bf16.  Block: 32 nodes x 256 ko.
__global__ __launch_bounds__(256) void k_P(const float* __restrict__ h, const float* __restrict__ Qt, u32* __restrict__ Pb){
  __shared__ float sQ[64*256];
  __shared__ float shh[32*64];
  int t = threadIdx.x;
  int nt = blockIdx.x >> 4, kt = blockIdx.x & 15;
  int nb = nt*32, kob = kt*256;
  const float4* Q4 = (const float4*)Qt;
  float4* sQ4 = (float4*)sQ;
  #pragma unroll
  for (int c = 0; c < 16; ++c) {
    int s4 = c*256 + t;
    int hh = s4 >> 6, j4 = s4 & 63;
    sQ4[s4] = Q4[hh*1024 + (kob>>2) + j4];
  }
  #pragma unroll
  for (int c = 0; c < 8; ++c) {
    int s = c*256 + t;
    int nl = s >> 6, hh = s & 63;
    int n = nb + nl;
    shh[s] = (n < NN) ? h[n*64 + hh] : 0.f;
  }
  __syncthreads();
  int tg = t >> 5, l5 = t & 31;
  int koff = l5*8;
  float acc[4][8];
  #pragma unroll
  for (int i=0;i<4;++i){
    #pragma unroll
    for (int j=0;j<8;++j) acc[i][j]=0.f;
  }
  #pragma unroll 4
  for (int hh = 0; hh < 64; ++hh) {
    float4 q0 = *(const float4*)&sQ[hh*256 + koff];
    float4 q1 = *(const float4*)&sQ[hh*256 + koff + 4];
    float qq[8] = {q0.x,q0.y,q0.z,q0.w,q1.x,q1.y,q1.z,q1.w};
    #pragma unroll
    for (int i=0;i<4;++i) {
      float a = shh[(tg*4+i)*64 + hh];
      #pragma unroll
      for (int j=0;j<8;++j) acc[i][j] = fmaf(a, qq[j], acc[i][j]);
    }
  }
  #pragma unroll
  for (int i=0;i<4;++i) {
    int n = nb + tg*4 + i;
    if (n < NN) {
      u32 o4[4];
      #pragma unroll
      for (int q=0;q<4;++q)
        o4[q] = f2bf(acc[i][2*q]) | (f2bf(acc[i][2*q+1])<<16);
      u32* dst = Pb + ((((size_t)n)*4096 + kob + koff) >> 1);
      *(uint4*)dst = make_uint4(o4[0],o4[1],o4[2],o4[3]);
    }
  }
}

// per-edge message: m[dst,o] += hb[src,o] + sum_k e1[e,k]*P[src,k*64+o]
__global__ __launch_bounds__(256) void k_msg(const int* __restrict__ ei, const u32* __restrict__ e1u,
                      const u32* __restrict__ Pb, const float* __restrict__ hb, float* __restrict__ m){
  int gt = blockIdx.x*256 + threadIdx.x;
  int e = gt >> 6, lane = gt & 63;
  int src = ei[e], dst = ei[NE + e];
  const unsigned short* Pr = (const unsigned short*)Pb + (size_t)src*4096;
  float acc = hb[src*64 + lane];
  #pragma unroll 4
  for (int k2 = 0; k2 < 32; ++k2) {
    u32 ew = e1u[e*32 + k2];
    acc = fmaf(bf2f(ew & 0xffffu), bf2f((u32)Pr[(2*k2)*64 + lane]), acc);
    acc = fmaf(bf2f(ew >> 16),     bf2f((u32)Pr[(2*k2+1)*64 + lane]), acc);
  }
  atomicAdd(&m[dst*64 + lane], acc);
}

// GRU: one wave per node
__global__ __launch_bounds__(256) void k_gru(const float* __restrict__ m, float* __restrict__ h,
                     const float* __restrict__ wihT, const float* __restrict__ whhT,
                     const float* __restrict__ bih, const float* __restrict__ bhh){
  __shared__ float sm[4][64], sh[4][64];
  int t = threadIdx.x, w = t>>6, lane = t&63;
  int n = blockIdx.x*4 + w;
  sm[w][lane] = m[n*64+lane];
  sh[w][lane] = h[n*64+lane];
  __syncthreads();
  float gi0=0,gi1=0,gi2=0,gh0=0,gh1=0,gh2=0;
  #pragma unroll 2
  for (int i=0;i<64;++i){
    float mi = sm[w][i], hi = sh[w][i];
    const float* wr = wihT + i*192;
    const float* ur = whhT + i*192;
    gi0=fmaf(mi, wr[lane],     gi0);
    gi1=fmaf(mi, wr[64+lane],  gi1);
    gi2=fmaf(mi, wr[128+lane], gi2);
    gh0=fmaf(hi, ur[lane],     gh0);
    gh1=fmaf(hi, ur[64+lane],  gh1);
    gh2=fmaf(hi, ur[128+lane], gh2);
  }
  float r  = sigm(gi0+bih[lane]     + gh0+bhh[lane]);
  float z  = sigm(gi1+bih[64+lane]  + gh1+bhh[64+lane]);
  float nn_= tanhf(gi2+bih[128+lane] + r*(gh2+bhh[128+lane]));
  float ho = sh[w][lane];
  h[n*64+lane] = (1.f-z)*nn_ + z*ho;
}

// h2 = cat(h, x) @ lin_w^T + lin_b : one wave per node, 2 outputs/lane
__global__ __launch_bounds__(256) void k_lin(const float* __restrict__ h, const float* __restrict__ x,
                     const float* __restrict__ linT, const float* __restrict__ lin_b, float* __restrict__ h2){
  __shared__ float sh[4][64];
  int t=threadIdx.x, w=t>>6, lane=t&63;
  int n = blockIdx.x*4 + w;
  sh[w][lane] = h[n*64+lane];
  __syncthreads();
  float a0 = lin_b[lane], a1 = lin_b[64+lane];
  #pragma unroll 4
  for (int i=0;i<64;++i){
    float v = sh[w][i];
    a0 = fmaf(v, linT[i*128+lane], a0);
    a1 = fmaf(v, linT[i*128+64+lane], a1);
  }
  #pragma unroll
  for (int i=0;i<11;++i){
    float v = x[n*NNF+i];
    a0 = fmaf(v, linT[(64+i)*128+lane], a0);
    a1 = fmaf(v, linT[(64+i)*128+64+lane], a1);
  }
  h2[n*128+lane] = a0;
  h2[n*128+64+lane] = a1;
}

// graph ranges via binary search on sorted batch
__global__ void k_bounds(const int* __restrict__ batch, int* __restrict__ gstart){
  int b = blockIdx.x*256 + threadIdx.x;
  if (b > BG) return;
  int lo=0, hi=NN;
  while (lo < hi){ int mid=(lo+hi)>>1; if (batch[mid] < b) lo=mid+1; else hi=mid; }
  gstart[b]=lo;
}

// LSTM gate pre-activations: g[b,j] = bih[j]+bhh[j] + in1[b]·w1T[:,j] + in2[b]·w2T[:,j]
__global__ void k_lstm_gemm(const float* __restrict__ in1, int D1, const float* __restrict__ w1T,
                            const float* __restrict__ in2, const float* __restrict__ w2T,
                            const float* __restrict__ bih, const float* __restrict__ bhh,
                            float* __restrict__ g){
  int tid = blockIdx.x*256 + threadIdx.x;
  int b = tid >> 9, j = tid & 511;
  float acc = bih[j] + bhh[j];
  const float* i1 = in1 + b*D1;
  for (int i=0;i<D1;++i) acc = fmaf(i1[i], w1T[i*512+j], acc);
  const float* i2 = in2 + b*128;
  #pragma unroll 4
  for (int i=0;i<128;++i) acc = fmaf(i2[i], w2T[i*512+j], acc);
  g[tid] = acc;
}

__global__ void k_lstm_act(const float* __restrict__ g, float* __restrict__ hS, float* __restrict__ cS){
  int tid = blockIdx.x*256 + threadIdx.x;
  int b = tid>>7, jj = tid&127;
  const float* gb = g + b*512;
  float ig = sigm(gb[jj]), fg = sigm(gb[128+jj]), gg = tanhf(gb[256+jj]), og = sigm(gb[384+jj]);
  float c = fg*cS[tid] + ig*gg;
  cS[tid] = c;
  hS[tid] = og*tanhf(c);
}

// per-graph online-softmax attention readout; one wave per graph; writes q_star=[q, r]
__global__ __launch_bounds__(256) void k_attn(const float* __restrict__ h2, const float* __restrict__ h1s,
                       const int* __restrict__ gstart, float* __restrict__ qstar){
  int t=threadIdx.x, w=t>>6, lane=t&63;
  int b = blockIdx.x*4 + w;
  float q0 = h1s[b*128+lane], q1 = h1s[b*128+64+lane];
  int s = gstart[b], epos = gstart[b+1];
  float mrun = -3.0e38f, l = 0.f, r0=0.f, r1=0.f;
  for (int n=s; n<epos; ++n){
    float v0 = h2[n*128+lane], v1 = h2[n*128+64+lane];
    float d = fmaf(v0, q0, v1*q1);
    #pragma unroll
    for (int off=32; off; off>>=1) d += __shfl_xor(d, off);
    float mn = fmaxf(mrun, d);
    float sc = __expf(mrun - mn);
    float ww = __expf(d - mn);
    l = l*sc + ww;
    r0 = r0*sc + ww*v0;
    r1 = r1*sc + ww*v1;
    mrun = mn;
  }
  float inv = (l > 0.f) ? 1.f/l : 0.f;
  qstar[b*256 + lane]       = q0;
  qstar[b*256 + 64 + lane]  = q1;
  qstar[b*256 + 128 + lane] = r0*inv;
  qstar[b*256 + 192 + lane] = r1*inv;
}

__global__ void k_mid(const float* __restrict__ qstar, const float* __restrict__ w2aT,
                      const float* __restrict__ b2a, float* __restrict__ midb){
  int tid = blockIdx.x*256+threadIdx.x;
  int b=tid>>9, j=tid&511;
  float acc=b2a[j];
  const float* q=qstar+b*256;
  #pragma unroll 4
  for(int i=0;i<256;++i) acc=fmaf(q[i], w2aT[i*512+j], acc);
  midb[tid]=fmaxf(acc,0.f);
}

__global__ void k_out(const float* __restrict__ midb, const float* __restrict__ w2b,
                      const float* __restrict__ b2b, float* __restrict__ out){
  int tid = blockIdx.x*256+threadIdx.x;
  if (tid >= BG*NT) return;
  int b=tid/NT, j=tid-b*NT;
  float acc=b2b[j];
  const float* mb=midb+b*512;
  const float* wr=w2b+j*512;
  #pragma unroll 4
  for(int i=0;i<512;++i) acc=fmaf(mb[i], wr[i], acc);
  out[tid]=acc;
}

extern "C" void kernel_launch(void* const* d_in, const int* in_sizes, int n_in,
                              void* d_out, int out_size, void* d_ws, size_t ws_size,
                              hipStream_t stream) {
  const float* x    = (const float*)d_in[0];
  const float* ea   = (const float*)d_in[1];
  const int*   eidx = (const int*)d_in[2];
  const int*   batch= (const int*)d_in[3];
  const float* w1a  = (const float*)d_in[5];
  const float* b1a  = (const float*)d_in[6];
  const float* w1b  = (const float*)d_in[7];
  const float* b1b  = (const float*)d_in[8];
  const float* w1c  = (const float*)d_in[9];
  const float* b1c  = (const float*)d_in[10];
  const float* gwih = (const float*)d_in[11];
  const float* gwhh = (const float*)d_in[12];
  const float* gbih = (const float*)d_in[13];
  const float* gbhh = (const float*)d_in[14];
  const float* linw = (const float*)d_in[15];
  const float* linb = (const float*)d_in[16];
  const float* wih0 = (const float*)d_in[17];
  const float* whh0 = (const float*)d_in[18];
  const float* bih0 = (const float*)d_in[19];
  const float* bhh0 = (const float*)d_in[20];
  const float* wih1 = (const float*)d_in[21];
  const float* whh1 = (const float*)d_in[22];
  const float* bih1 = (const float*)d_in[23];
  const float* bhh1 = (const float*)d_in[24];
  const float* w2a  = (const float*)d_in[25];
  const float* b2a  = (const float*)d_in[26];
  const float* w2b  = (const float*)d_in[27];
  const float* b2b  = (const float*)d_in[28];
  float* out = (float*)d_out;

  char* p = (char*)d_ws;
  auto alloc = [&](size_t nbytes){ void* r = (void*)p; p += (nbytes + 255) & ~size_t(255); return r; };
  float* h    = (float*)alloc((size_t)NN*64*4);
  float* hb   = (float*)alloc((size_t)NN*64*4);
  float* m    = (float*)alloc((size_t)NN*64*4);
  float* h2   = (float*)alloc((size_t)NN*128*4);
  float* wihT = (float*)alloc(64*192*4);
  float* whhT = (float*)alloc(64*192*4);
  float* linT = (float*)alloc(75*128*4);
  float* w1bT = (float*)alloc(64*64*4);
  float* wih0T= (float*)alloc(256*512*4);
  float* whh0T= (float*)alloc(128*512*4);
  float* wih1T= (float*)alloc(128*512*4);
  float* whh1T= (float*)alloc(128*512*4);
  float* w2aT = (float*)alloc(256*512*4);
  float* qstar= (float*)alloc(256*256*4);
  float* h0   = (float*)alloc(256*128*4);
  float* c0   = (float*)alloc(256*128*4);
  float* h1s  = (float*)alloc(256*128*4);
  float* c1   = (float*)alloc(256*128*4);
  float* g    = (float*)alloc(256*512*4);
  float* midb = (float*)alloc(256*512*4);
  float* Qt   = (float*)alloc(64*4096*4);
  int*  gstart= (int*)alloc(257*4);
  unsigned short* e1b = (unsigned short*)alloc((size_t)NE*64*2);
  u32*  Pb    = (u32*)alloc((size_t)NN*4096*2);

  k_h_init<<<2500, 256, 0, stream>>>(x, h);
  k_T<<<48, 256, 0, stream>>>(gwih, wihT, 192, 64);
  k_T<<<48, 256, 0, stream>>>(gwhh, whhT, 192, 64);
  k_T<<<38, 256, 0, stream>>>(linw, linT, 128, 75);
  k_T<<<16, 256, 0, stream>>>(w1b, w1bT, 64, 64);
  k_T<<<512, 256, 0, stream>>>(wih0, wih0T, 512, 256);
  k_T<<<256, 256, 0, stream>>>(whh0, whh0T, 512, 128);
  k_T<<<256, 256, 0, stream>>>(wih1, wih1T, 512, 128);
  k_T<<<256, 256, 0, stream>>>(whh1, whh1T, 512, 128);
  k_T<<<512, 256, 0, stream>>>(w2a, w2aT, 512, 256);
  k_qt<<<1024, 256, 0, stream>>>(w1c, Qt);
  k_e1<<<12500, 256, 0, stream>>>(ea, w1a, b1a, w1bT, b1b, e1b);
  k_bounds<<<2, 256, 0, stream>>>(batch, gstart);
  hipMemsetAsync(qstar, 0, (256*256 + 4*256*128)*4, stream);

  for (int t = 0; t < 3; ++t) {
    k_hb<<<2500, 256, 0, stream>>>(h, b1c, hb);
    k_P<<<313*16, 256, 0, stream>>>(h, Qt, Pb);
    hipMemsetAsync(m, 0, (size_t)NN*64*4, stream);
    k_msg<<<12500, 256, 0, stream>>>(eidx, (const u32*)e1b, Pb, hb, m);
    k_gru<<<2500, 256, 0, stream>>>(m, h, wihT, whhT, gbih, gbhh);
  }

  k_lin<<<2500, 256, 0, stream>>>(h, x, linT, linb, h2);

  for (int s = 0; s < 3; ++s) {
    k_lstm_gemm<<<512, 256, 0, stream>>>(qstar, 256, wih0T, h0, whh0T, bih0, bhh0, g);
    k_lstm_act<<<128, 256, 0, stream>>>(g, h0, c0);
    k_lstm_gemm<<<512, 256, 0, stream>>>(h0, 128, wih1T, h1s, whh1T, bih1, bhh1, g);
    k_lstm_act<<<128, 256, 0, stream>>>(g, h1s, c1);
    k_attn<<<64, 256, 0, stream>>>(h2, h1s, gstart, qstar);
  }

  k_mid<<<512, 256, 0, stream>>>(qstar, w2aT, b2a, midb);
  k_out<<<12, 256, 0, stream>>>(midb, w2b, b2b, out);
}

// Round 2
// 1017.806 us; speedup vs baseline: 1.1147x; 1.1147x over previous
//
#include <hip/hip_runtime.h>
#include <math.h>

#define NN 10000
#define NE 50000
#define BG 256
#define NNF 11
#define NT 12

typedef unsigned int u32;
typedef __attribute__((ext_vector_type(8))) short short8v;   // 8 bf16 (4 VGPRs)
typedef __attribute__((ext_vector_type(4))) float f32x4;

__device__ __forceinline__ float sigm(float x){ return 1.0f/(1.0f+__expf(-x)); }
__device__ __forceinline__ u32 f2bf(float f){
  u32 u = __float_as_uint(f);
  return (u + 0x7fffu + ((u>>16)&1u)) >> 16;   // RNE
}
__device__ __forceinline__ float bf2f(u32 s){ return __uint_as_float(s<<16); }

// h[n,j] = j<11 ? x[n,j] : 0
__global__ void k_h_init(const float* __restrict__ x, float* __restrict__ h){
  int tid = blockIdx.x*256 + threadIdx.x;
  if (tid >= NN*64) return;
  int n = tid >> 6, j = tid & 63;
  h[tid] = (j < NNF) ? x[n*NNF + j] : 0.0f;
}

// generic transpose: in [R][C] -> out [C][R]
__global__ void k_T(const float* __restrict__ in, float* __restrict__ out, int R, int C){
  int tid = blockIdx.x*256 + threadIdx.x;
  if (tid >= R*C) return;
  int i = tid / C, j = tid - i*C;
  out[j*R + i] = in[i*C + j];
}

// qtT[ko*64+hh] = bf16(w1c[(hh*64+o)*64+k]), ko=k*64+o  -- B^T operand for MFMA
__global__ void k_qtt(const float* __restrict__ w1c, unsigned short* __restrict__ qtT){
  int tid = blockIdx.x*256 + threadIdx.x;   // 262144 total
  int ko = tid >> 6, hh = tid & 63;
  int k = ko >> 6, o = ko & 63;
  qtT[tid] = (unsigned short)f2bf(w1c[(hh*64 + o)*64 + k]);
}

// split h fp32 -> bf16 hi + bf16 lo (residual), for 2-pass exact-ish MFMA A operand
__global__ void k_hsplit(const float* __restrict__ h, unsigned short* __restrict__ hi,
                         unsigned short* __restrict__ lo){
  int tid = blockIdx.x*256 + threadIdx.x;
  if (tid >= NN*64) return;
  float v = h[tid];
  u32 hv = f2bf(v);
  hi[tid] = (unsigned short)hv;
  lo[tid] = (unsigned short)f2bf(v - bf2f(hv));
}

// edge MLP: e1 = relu(relu(ea@w1a^T+b1a)@w1b^T+b1b), stored bf16 (pairs little-endian in u32)
__global__ __launch_bounds__(256) void k_e1(const float* __restrict__ ea, const float* __restrict__ w1a,
                     const float* __restrict__ b1a, const float* __restrict__ w1bT,
                     const float* __restrict__ b1b, unsigned short* __restrict__ e1b){
  __shared__ float sw[64*64];
  __shared__ float sh1[4][64];
  int t = threadIdx.x;
  #pragma unroll
  for (int c = 0; c < 16; ++c) sw[c*256 + t] = w1bT[c*256 + t];
  int w = t >> 6, lane = t & 63;
  int e = blockIdx.x*4 + w;
  float h1 = 0.f;
  if (e < NE) {
    float a0 = ea[e*4+0], a1 = ea[e*4+1], a2 = ea[e*4+2], a3 = ea[e*4+3];
    h1 = b1a[lane] + a0*w1a[lane*4+0] + a1*w1a[lane*4+1] + a2*w1a[lane*4+2] + a3*w1a[lane*4+3];
    h1 = fmaxf(h1, 0.f);
  }
  sh1[w][lane] = h1;
  __syncthreads();
  if (e < NE) {
    float acc = b1b[lane];
    #pragma unroll 8
    for (int i = 0; i < 64; ++i) acc = fmaf(sh1[w][i], sw[i*64 + lane], acc);
    e1b[e*64 + lane] = (unsigned short)f2bf(fmaxf(acc, 0.f));
  }
}

// hb[n,o] = sum_h h[n,h]*b1c[h*64+o]
__global__ void k_hb(const float* __restrict__ h, const float* __restrict__ b1c, float* __restrict__ hb){
  int tid = blockIdx.x*256 + threadIdx.x;
  int n = tid >> 6, o = tid & 63;
  const float* hr = h + n*64;
  float acc = 0.f;
  #pragma unroll 8
  for (int i = 0; i < 64; ++i) acc = fmaf(hr[i], b1c[i*64 + o], acc);
  hb[tid] = acc;
}

// P2[n][k2*64+o] = pack(bf16 P[n][2k2*64+o], bf16 P[n][(2k2+1)*64+o])
// where P[n][k*64+o] = sum_h h[n,h]*w1c[(h*64+o)*64+k].  MFMA version.
// Block: 4 waves; wave w = 16 nodes x 256 kos; grid = 157 node-tiles x 16 ko-tiles.
__global__ __launch_bounds__(256) void k_P2(const unsigned short* __restrict__ hHi,
                      const unsigned short* __restrict__ hLo,
                      const unsigned short* __restrict__ qtT, u32* __restrict__ P2){
  int t = threadIdx.x; int w = t >> 6; int l = t & 63;
  int c = l & 15, g = l >> 4;
  int nt = blockIdx.x >> 4, kt = blockIdx.x & 15;
  int nb = nt*64 + w*16;
  int kob = kt*256;
  int rowA = nb + c; if (rowA >= NN) rowA = NN-1;
  const short8v* aHiP = (const short8v*)((const short*)hHi + rowA*64 + g*8);
  const short8v* aLoP = (const short8v*)((const short*)hLo + rowA*64 + g*8);
  short8v aH0 = aHiP[0], aH1 = aHiP[4];      // k 0..31, 32..63 (this lane's 8-slice)
  short8v aL0 = aLoP[0], aL1 = aLoP[4];
  const short* qb = (const short*)qtT + (size_t)(kob + c)*64 + g*8;
  f32x4 acc[16];
  #pragma unroll
  for (int f = 0; f < 16; ++f) acc[f] = f32x4{0.f,0.f,0.f,0.f};
  #pragma unroll
  for (int f = 0; f < 16; ++f){
    short8v b0 = *(const short8v*)(qb + f*1024);
    short8v b1 = *(const short8v*)(qb + f*1024 + 32);
    acc[f] = __builtin_amdgcn_mfma_f32_16x16x32_bf16(aH0, b0, acc[f], 0, 0, 0);
    acc[f] = __builtin_amdgcn_mfma_f32_16x16x32_bf16(aL0, b0, acc[f], 0, 0, 0);
    acc[f] = __builtin_amdgcn_mfma_f32_16x16x32_bf16(aH1, b1, acc[f], 0, 0, 0);
    acc[f] = __builtin_amdgcn_mfma_f32_16x16x32_bf16(aL1, b1, acc[f], 0, 0, 0);
  }
  // frag f covers cols kob + f*16 + c: k = kob/64 + (f>>2), o = (f&3)*16 + c.
  // pair (f, f+4) -> same o, k even/odd -> one u32 of P2.
  int k2b = kt*2;
  #pragma unroll
  for (int r = 0; r < 4; ++r){
    int node = nb + 4*g + r;                  // C/D: row = 4*(lane>>4)+reg [m89-verified]
    if (node < NN){
      u32* dst = P2 + (size_t)node*2048;
      #pragma unroll
      for (int fp = 0; fp < 8; ++fp){
        int f = fp + ((fp >> 2) << 2);        // {0,1,2,3,8,9,10,11}
        u32 val = f2bf(acc[f][r]) | (f2bf(acc[f+4][r]) << 16);
        dst[(k2b + (fp >> 2))*64 + (fp & 3)*16 + c] = val;
      }
    }
  }
}

// ---- CSR build (by src) ----
__global__ void k_deg(const int* __restrict__ ei, int* __restrict__ deg){
  int e = blockIdx.x*256 + threadIdx.x;
  if (e >= NE) return;
  atomicAdd(&deg[ei[e]], 1);
}

__global__ __launch_bounds__(256) void k_scan(const int* __restrict__ deg, int* __restrict__ rowptr,
                       int* __restrict__ cursor){
  __shared__ int part[256];
  int t = threadIdx.x;
  int base = t*40;
  int s = 0;
  for (int i = 0; i < 40; ++i){ int idx = base+i; if (idx < NN) s += deg[idx]; }
  part[t] = s;
  __syncthreads();
  for (int off = 1; off < 256; off <<= 1){
    int v = (t >= off) ? part[t-off] : 0;
    __syncthreads();
    part[t] += v;
    __syncthreads();
  }
  int run = (t == 0) ? 0 : part[t-1];
  for (int i = 0; i < 40; ++i){
    int idx = base+i;
    if (idx < NN){ rowptr[idx] = run; cursor[idx] = run; run += deg[idx]; }
  }
  if (t == 255) rowptr[NN] = part[255];
}

__global__ void k_fill(const int* __restrict__ ei, int* __restrict__ cursor, int* __restrict__ csr_e){
  int e = blockIdx.x*256 + threadIdx.x;
  if (e >= NE) return;
  int s = ei[e];
  int pos = atomicAdd(&cursor[s], 1);
  csr_e[pos] = e;
}

// message pass, CSR by src: one wave per node; P2 row in registers; loop out-edges.
__global__ __launch_bounds__(256) void k_msg2(const int* __restrict__ rowptr, const int* __restrict__ csr_e,
                       const int* __restrict__ ei, const u32* __restrict__ e1u,
                       const u32* __restrict__ P2, const float* __restrict__ hb,
                       float* __restrict__ m){
  int t = threadIdx.x; int w = t >> 6; int o = t & 63;
  int n = blockIdx.x*4 + w;
  int jb = rowptr[n], je = rowptr[n+1];
  if (jb == je) return;
  float hbv = hb[n*64 + o];
  const u32* Pn = P2 + (size_t)n*2048;
  u32 pr[32];
  #pragma unroll
  for (int k2 = 0; k2 < 32; ++k2) pr[k2] = Pn[k2*64 + o];
  for (int j = jb; j < je; ++j){
    int e = csr_e[j];
    int dst = ei[NE + e];
    const u32* er = e1u + e*32;
    float acc = hbv;
    #pragma unroll 8
    for (int k2 = 0; k2 < 32; ++k2){
      u32 ew = er[k2];
      u32 pv = pr[k2];
      acc = fmaf(bf2f(ew & 0xffffu), bf2f(pv & 0xffffu), acc);
      acc = fmaf(bf2f(ew >> 16),     bf2f(pv >> 16),     acc);
    }
    atomicAdd(&m[dst*64 + o], acc);
  }
}

// GRU: one wave per node
__global__ __launch_bounds__(256) void k_gru(const float* __restrict__ m, float* __restrict__ h,
                     const float* __restrict__ wihT, const float* __restrict__ whhT,
                     const float* __restrict__ bih, const float* __restrict__ bhh){
  __shared__ float sm[4][64], sh[4][64];
  int t = threadIdx.x, w = t>>6, lane = t&63;
  int n = blockIdx.x*4 + w;
  sm[w][lane] = m[n*64+lane];
  sh[w][lane] = h[n*64+lane];
  __syncthreads();
  float gi0=0,gi1=0,gi2=0,gh0=0,gh1=0,gh2=0;
  #pragma unroll 2
  for (int i=0;i<64;++i){
    float mi = sm[w][i], hi = sh[w][i];
    const float* wr = wihT + i*192;
    const float* ur = whhT + i*192;
    gi0=fmaf(mi, wr[lane],     gi0);
    gi1=fmaf(mi, wr[64+lane],  gi1);
    gi2=fmaf(mi, wr[128+lane], gi2);
    gh0=fmaf(hi, ur[lane],     gh0);
    gh1=fmaf(hi, ur[64+lane],  gh1);
    gh2=fmaf(hi, ur[128+lane], gh2);
  }
  float r  = sigm(gi0+bih[lane]     + gh0+bhh[lane]);
  float z  = sigm(gi1+bih[64+lane]  + gh1+bhh[64+lane]);
  float nn_= tanhf(gi2+bih[128+lane] + r*(gh2+bhh[128+lane]));
  float ho = sh[w][lane];
  h[n*64+lane] = (1.f-z)*nn_ + z*ho;
}

// h2 = cat(h, x) @ lin_w^T + lin_b
__global__ __launch_bounds__(256) void k_lin(const float* __restrict__ h, const float* __restrict__ x,
                     const float* __restrict__ linT, const float* __restrict__ lin_b, float* __restrict__ h2){
  __shared__ float sh[4][64];
  int t=threadIdx.x, w=t>>6, lane=t&63;
  int n = blockIdx.x*4 + w;
  sh[w][lane] = h[n*64+lane];
  __syncthreads();
  float a0 = lin_b[lane], a1 = lin_b[64+lane];
  #pragma unroll 4
  for (int i=0;i<64;++i){
    float v = sh[w][i];
    a0 = fmaf(v, linT[i*128+lane], a0);
    a1 = fmaf(v, linT[i*128+64+lane], a1);
  }
  #pragma unroll
  for (int i=0;i<11;++i){
    float v = x[n*NNF+i];
    a0 = fmaf(v, linT[(64+i)*128+lane], a0);
    a1 = fmaf(v, linT[(64+i)*128+64+lane], a1);
  }
  h2[n*128+lane] = a0;
  h2[n*128+64+lane] = a1;
}

// graph ranges via binary search on sorted batch
__global__ void k_bounds(const int* __restrict__ batch, int* __restrict__ gstart){
  int b = blockIdx.x*256 + threadIdx.x;
  if (b > BG) return;
  int lo=0, hi=NN;
  while (lo < hi){ int mid=(lo+hi)>>1; if (batch[mid] < b) lo=mid+1; else hi=mid; }
  gstart[b]=lo;
}

// LSTM gate pre-activations
__global__ void k_lstm_gemm(const float* __restrict__ in1, int D1, const float* __restrict__ w1T,
                            const float* __restrict__ in2, const float* __restrict__ w2T,
                            const float* __restrict__ bih, const float* __restrict__ bhh,
                            float* __restrict__ g){
  int tid = blockIdx.x*256 + threadIdx.x;
  int b = tid >> 9, j = tid & 511;
  float acc = bih[j] + bhh[j];
  const float* i1 = in1 + b*D1;
  for (int i=0;i<D1;++i) acc = fmaf(i1[i], w1T[i*512+j], acc);
  const float* i2 = in2 + b*128;
  #pragma unroll 4
  for (int i=0;i<128;++i) acc = fmaf(i2[i], w2T[i*512+j], acc);
  g[tid] = acc;
}

__global__ void k_lstm_act(const float* __restrict__ g, float* __restrict__ hS, float* __restrict__ cS){
  int tid = blockIdx.x*256 + threadIdx.x;
  int b = tid>>7, jj = tid&127;
  const float* gb = g + b*512;
  float ig = sigm(gb[jj]), fg = sigm(gb[128+jj]), gg = tanhf(gb[256+jj]), og = sigm(gb[384+jj]);
  float c = fg*cS[tid] + ig*gg;
  cS[tid] = c;
  hS[tid] = og*tanhf(c);
}

// per-graph online-softmax attention readout
__global__ __launch_bounds__(256) void k_attn(const float* __restrict__ h2, const float* __restrict__ h1s,
                       const int* __restrict__ gstart, float* __restrict__ qstar){
  int t=threadIdx.x, w=t>>6, lane=t&63;
  int b = blockIdx.x*4 + w;
  float q0 = h1s[b*128+lane], q1 = h1s[b*128+64+lane];
  int s = gstart[b], epos = gstart[b+1];
  float mrun = -3.0e38f, l = 0.f, r0=0.f, r1=0.f;
  for (int n=s; n<epos; ++n){
    float v0 = h2[n*128+lane], v1 = h2[n*128+64+lane];
    float d = fmaf(v0, q0, v1*q1);
    #pragma unroll
    for (int off=32; off; off>>=1) d += __shfl_xor(d, off);
    float mn = fmaxf(mrun, d);
    float sc = __expf(mrun - mn);
    float ww = __expf(d - mn);
    l = l*sc + ww;
    r0 = r0*sc + ww*v0;
    r1 = r1*sc + ww*v1;
    mrun = mn;
  }
  float inv = (l > 0.f) ? 1.f/l : 0.f;
  qstar[b*256 + lane]       = q0;
  qstar[b*256 + 64 + lane]  = q1;
  qstar[b*256 + 128 + lane] = r0*inv;
  qstar[b*256 + 192 + lane] = r1*inv;
}

__global__ void k_mid(const float* __restrict__ qstar, const float* __restrict__ w2aT,
                      const float* __restrict__ b2a, float* __restrict__ midb){
  int tid = blockIdx.x*256+threadIdx.x;
  int b=tid>>9, j=tid&511;
  float acc=b2a[j];
  const float* q=qstar+b*256;
  #pragma unroll 4
  for(int i=0;i<256;++i) acc=fmaf(q[i], w2aT[i*512+j], acc);
  midb[tid]=fmaxf(acc,0.f);
}

__global__ void k_out(const float* __restrict__ midb, const float* __restrict__ w2b,
                      const float* __restrict__ b2b, float* __restrict__ out){
  int tid = blockIdx.x*256+threadIdx.x;
  if (tid >= BG*NT) return;
  int b=tid/NT, j=tid-b*NT;
  float acc=b2b[j];
  const float* mb=midb+b*512;
  const float* wr=w2b+j*512;
  #pragma unroll 4
  for(int i=0;i<512;++i) acc=fmaf(mb[i], wr[i], acc);
  out[tid]=acc;
}

extern "C" void kernel_launch(void* const* d_in, const int* in_sizes, int n_in,
                              void* d_out, int out_size, void* d_ws, size_t ws_size,
                              hipStream_t stream) {
  const float* x    = (const float*)d_in[0];
  const float* ea   = (const float*)d_in[1];
  const int*   eidx = (const int*)d_in[2];
  const int*   batch= (const int*)d_in[3];
  const float* w1a  = (const float*)d_in[5];
  const float* b1a  = (const float*)d_in[6];
  const float* w1b  = (const float*)d_in[7];
  const float* b1b  = (const float*)d_in[8];
  const float* w1c  = (const float*)d_in[9];
  const float* b1c  = (const float*)d_in[10];
  const float* gwih = (const float*)d_in[11];
  const float* gwhh = (const float*)d_in[12];
  const float* gbih = (const float*)d_in[13];
  const float* gbhh = (const float*)d_in[14];
  const float* linw = (const float*)d_in[15];
  const float* linb = (const float*)d_in[16];
  const float* wih0 = (const float*)d_in[17];
  const float* whh0 = (const float*)d_in[18];
  const float* bih0 = (const float*)d_in[19];
  const float* bhh0 = (const float*)d_in[20];
  const float* wih1 = (const float*)d_in[21];
  const float* whh1 = (const float*)d_in[22];
  const float* bih1 = (const float*)d_in[23];
  const float* bhh1 = (const float*)d_in[24];
  const float* w2a  = (const float*)d_in[25];
  const float* b2a  = (const float*)d_in[26];
  const float* w2b  = (const float*)d_in[27];
  const float* b2b  = (const float*)d_in[28];
  float* out = (float*)d_out;

  char* p = (char*)d_ws;
  auto alloc = [&](size_t nbytes){ void* r = (void*)p; p += (nbytes + 255) & ~size_t(255); return r; };
  float* h    = (float*)alloc((size_t)NN*64*4);
  float* hb   = (float*)alloc((size_t)NN*64*4);
  float* m    = (float*)alloc((size_t)NN*64*4);
  float* h2   = (float*)alloc((size_t)NN*128*4);
  float* wihT = (float*)alloc(64*192*4);
  float* whhT = (float*)alloc(64*192*4);
  float* linT = (float*)alloc(75*128*4);
  float* w1bT = (float*)alloc(64*64*4);
  float* wih0T= (float*)alloc(256*512*4);
  float* whh0T= (float*)alloc(128*512*4);
  float* wih1T= (float*)alloc(128*512*4);
  float* whh1T= (float*)alloc(128*512*4);
  float* w2aT = (float*)alloc(256*512*4);
  float* qstar= (float*)alloc(256*256*4);
  float* h0   = (float*)alloc(256*128*4);
  float* c0   = (float*)alloc(256*128*4);
  float* h1s  = (float*)alloc(256*128*4);
  float* c1   = (float*)alloc(256*128*4);
  float* g    = (float*)alloc(256*512*4);
  float* midb = (float*)alloc(256*512*4);
  int*  gstart= (int*)alloc(257*4);
  unsigned short* e1b = (unsigned short*)alloc((size_t)NE*64*2);
  unsigned short* qtT = (unsigned short*)alloc((size_t)4096*64*2);
  unsigned short* hHi = (unsigned short*)alloc((size_t)NN*64*2);
  unsigned short* hLo = (unsigned short*)alloc((size_t)NN*64*2);
  int*  deg   = (int*)alloc((size_t)NN*4);
  int*  rowptr= (int*)alloc((size_t)(NN+1)*4);
  int*  cursor= (int*)alloc((size_t)NN*4);
  int*  csr_e = (int*)alloc((size_t)NE*4);
  u32*  P2    = (u32*)alloc((size_t)NN*2048*4);

  k_h_init<<<2500, 256, 0, stream>>>(x, h);
  k_T<<<48, 256, 0, stream>>>(gwih, wihT, 192, 64);
  k_T<<<48, 256, 0, stream>>>(gwhh, whhT, 192, 64);
  k_T<<<38, 256, 0, stream>>>(linw, linT, 128, 75);
  k_T<<<16, 256, 0, stream>>>(w1b, w1bT, 64, 64);
  k_T<<<512, 256, 0, stream>>>(wih0, wih0T, 512, 256);
  k_T<<<256, 256, 0, stream>>>(whh0, whh0T, 512, 128);
  k_T<<<256, 256, 0, stream>>>(wih1, wih1T, 512, 128);
  k_T<<<256, 256, 0, stream>>>(whh1, whh1T, 512, 128);
  k_T<<<512, 256, 0, stream>>>(w2a, w2aT, 512, 256);
  k_qtt<<<1024, 256, 0, stream>>>(w1c, qtT);
  k_e1<<<12500, 256, 0, stream>>>(ea, w1a, b1a, w1bT, b1b, e1b);
  k_bounds<<<2, 256, 0, stream>>>(batch, gstart);
  hipMemsetAsync(qstar, 0, (256*256 + 4*256*128)*4, stream);

  // CSR by src (rebuilt every call; ws is re-poisoned)
  hipMemsetAsync(deg, 0, (size_t)NN*4, stream);
  k_deg<<<196, 256, 0, stream>>>(eidx, deg);
  k_scan<<<1, 256, 0, stream>>>(deg, rowptr, cursor);
  k_fill<<<196, 256, 0, stream>>>(eidx, cursor, csr_e);

  for (int t = 0; t < 3; ++t) {
    k_hb<<<2500, 256, 0, stream>>>(h, b1c, hb);
    k_hsplit<<<2500, 256, 0, stream>>>(h, hHi, hLo);
    k_P2<<<157*16, 256, 0, stream>>>(hHi, hLo, qtT, P2);
    hipMemsetAsync(m, 0, (size_t)NN*64*4, stream);
    k_msg2<<<2500, 256, 0, stream>>>(rowptr, csr_e, eidx, (const u32*)e1b, P2, hb, m);
    k_gru<<<2500, 256, 0, stream>>>(m, h, wihT, whhT, gbih, gbhh);
  }

  k_lin<<<2500, 256, 0, stream>>>(h, x, linT, linb, h2);

  for (int s = 0; s < 3; ++s) {
    k_lstm_gemm<<<512, 256, 0, stream>>>(qstar, 256, wih0T, h0, whh0T, bih0, bhh0, g);
    k_lstm_act<<<128, 256, 0, stream>>>(g, h0, c0);
    k_lstm_gemm<<<512, 256, 0, stream>>>(h0, 128, wih1T, h1s, whh1T, bih1, bhh1, g);
    k_lstm_act<<<128, 256, 0, stream>>>(g, h1s, c1);
    k_attn<<<64, 256, 0, stream>>>(h2, h1s, gstart, qstar);
  }

  k_mid<<<512, 256, 0, stream>>>(qstar, w2aT, b2a, midb);
  k_out<<<12, 256, 0, stream>>>(midb, w2b, b2b, out);
}

// Round 3
// 810.888 us; speedup vs baseline: 1.3992x; 1.2552x over previous
//
#include <hip/hip_runtime.h>
#include <math.h>

#define NN 10000
#define NE 50000
#define BG 256
#define NNF 11
#define NT 12

typedef unsigned int u32;
typedef __attribute__((ext_vector_type(8))) short short8v;   // 8 bf16 (4 VGPRs)
typedef __attribute__((ext_vector_type(4))) float f32x4;

__device__ __forceinline__ float sigm(float x){ return 1.0f/(1.0f+__expf(-x)); }
__device__ __forceinline__ u32 f2bf(float f){
  u32 u = __float_as_uint(f);
  return (u + 0x7fffu + ((u>>16)&1u)) >> 16;   // RNE
}
__device__ __forceinline__ float bf2f(u32 s){ return __uint_as_float(s<<16); }

// h[n,j] = j<11 ? x[n,j] : 0 ; also emit bf16 hi/lo split
__global__ void k_h_init(const float* __restrict__ x, float* __restrict__ h,
                         unsigned short* __restrict__ hHi, unsigned short* __restrict__ hLo){
  int tid = blockIdx.x*256 + threadIdx.x;
  if (tid >= NN*64) return;
  int n = tid >> 6, j = tid & 63;
  float v = (j < NNF) ? x[n*NNF + j] : 0.0f;
  h[tid] = v;
  u32 hv = f2bf(v);
  hHi[tid] = (unsigned short)hv;
  hLo[tid] = (unsigned short)f2bf(v - bf2f(hv));
}

// generic transpose: in [R][C] -> out [C][R]
__global__ void k_T(const float* __restrict__ in, float* __restrict__ out, int R, int C){
  int tid = blockIdx.x*256 + threadIdx.x;
  if (tid >= R*C) return;
  int i = tid / C, j = tid - i*C;
  out[j*R + i] = in[i*C + j];
}

// qtT[ko*64+hh] = bf16(w1c[(hh*64+o)*64+k]), ko=k*64+o  -- B^T operand for MFMA
__global__ void k_qtt(const float* __restrict__ w1c, unsigned short* __restrict__ qtT){
  int tid = blockIdx.x*256 + threadIdx.x;   // 262144 total
  int ko = tid >> 6, hh = tid & 63;
  int k = ko >> 6, o = ko & 63;
  qtT[tid] = (unsigned short)f2bf(w1c[(hh*64 + o)*64 + k]);
}

// edge MLP: e1 = relu(relu(ea@w1a^T+b1a)@w1b^T+b1b), stored bf16 (pairs little-endian in u32)
__global__ __launch_bounds__(256) void k_e1(const float* __restrict__ ea, const float* __restrict__ w1a,
                     const float* __restrict__ b1a, const float* __restrict__ w1bT,
                     const float* __restrict__ b1b, unsigned short* __restrict__ e1b){
  __shared__ float sw[64*64];
  __shared__ float sh1[4][64];
  int t = threadIdx.x;
  #pragma unroll
  for (int c = 0; c < 16; ++c) sw[c*256 + t] = w1bT[c*256 + t];
  int w = t >> 6, lane = t & 63;
  int e = blockIdx.x*4 + w;
  float h1 = 0.f;
  if (e < NE) {
    float a0 = ea[e*4+0], a1 = ea[e*4+1], a2 = ea[e*4+2], a3 = ea[e*4+3];
    h1 = b1a[lane] + a0*w1a[lane*4+0] + a1*w1a[lane*4+1] + a2*w1a[lane*4+2] + a3*w1a[lane*4+3];
    h1 = fmaxf(h1, 0.f);
  }
  sh1[w][lane] = h1;
  __syncthreads();
  if (e < NE) {
    float acc = b1b[lane];
    #pragma unroll 8
    for (int i = 0; i < 64; ++i) acc = fmaf(sh1[w][i], sw[i*64 + lane], acc);
    e1b[e*64 + lane] = (unsigned short)f2bf(fmaxf(acc, 0.f));
  }
}

// hb[n,o] = sum_h h[n,h]*b1c[h*64+o]
__global__ void k_hb(const float* __restrict__ h, const float* __restrict__ b1c, float* __restrict__ hb){
  int tid = blockIdx.x*256 + threadIdx.x;
  int n = tid >> 6, o = tid & 63;
  const float* hr = h + n*64;
  float acc = 0.f;
  #pragma unroll 8
  for (int i = 0; i < 64; ++i) acc = fmaf(hr[i], b1c[i*64 + o], acc);
  hb[tid] = acc;
}

// P2[n][k2*64+o] = pack(bf16 P[n][2k2*64+o], bf16 P[n][(2k2+1)*64+o])  (MFMA)
__global__ __launch_bounds__(256) void k_P2(const unsigned short* __restrict__ hHi,
                      const unsigned short* __restrict__ hLo,
                      const unsigned short* __restrict__ qtT, u32* __restrict__ P2){
  int t = threadIdx.x; int w = t >> 6; int l = t & 63;
  int c = l & 15, g = l >> 4;
  int nt = blockIdx.x >> 4, kt = blockIdx.x & 15;
  int nb = nt*64 + w*16;
  int kob = kt*256;
  int rowA = nb + c; if (rowA >= NN) rowA = NN-1;
  const short8v* aHiP = (const short8v*)((const short*)hHi + rowA*64 + g*8);
  const short8v* aLoP = (const short8v*)((const short*)hLo + rowA*64 + g*8);
  short8v aH0 = aHiP[0], aH1 = aHiP[4];
  short8v aL0 = aLoP[0], aL1 = aLoP[4];
  const short* qb = (const short*)qtT + (size_t)(kob + c)*64 + g*8;
  f32x4 acc[16];
  #pragma unroll
  for (int f = 0; f < 16; ++f) acc[f] = f32x4{0.f,0.f,0.f,0.f};
  #pragma unroll
  for (int f = 0; f < 16; ++f){
    short8v b0 = *(const short8v*)(qb + f*1024);
    short8v b1 = *(const short8v*)(qb + f*1024 + 32);
    acc[f] = __builtin_amdgcn_mfma_f32_16x16x32_bf16(aH0, b0, acc[f], 0, 0, 0);
    acc[f] = __builtin_amdgcn_mfma_f32_16x16x32_bf16(aL0, b0, acc[f], 0, 0, 0);
    acc[f] = __builtin_amdgcn_mfma_f32_16x16x32_bf16(aH1, b1, acc[f], 0, 0, 0);
    acc[f] = __builtin_amdgcn_mfma_f32_16x16x32_bf16(aL1, b1, acc[f], 0, 0, 0);
  }
  int k2b = kt*2;
  #pragma unroll
  for (int r = 0; r < 4; ++r){
    int node = nb + 4*g + r;
    if (node < NN){
      u32* dst = P2 + (size_t)node*2048;
      #pragma unroll
      for (int fp = 0; fp < 8; ++fp){
        int f = fp + ((fp >> 2) << 2);        // {0,1,2,3,8,9,10,11}
        u32 val = f2bf(acc[f][r]) | (f2bf(acc[f+4][r]) << 16);
        dst[(k2b + (fp >> 2))*64 + (fp & 3)*16 + c] = val;
      }
    }
  }
}

// ---- CSR build (by src) ----
__global__ void k_deg(const int* __restrict__ ei, int* __restrict__ deg){
  int e = blockIdx.x*256 + threadIdx.x;
  if (e >= NE) return;
  atomicAdd(&deg[ei[e]], 1);
}

__global__ __launch_bounds__(256) void k_scan(const int* __restrict__ deg, int* __restrict__ rowptr,
                       int* __restrict__ cursor){
  __shared__ int part[256];
  int t = threadIdx.x;
  int base = t*40;
  int s = 0;
  for (int i = 0; i < 40; ++i){ int idx = base+i; if (idx < NN) s += deg[idx]; }
  part[t] = s;
  __syncthreads();
  for (int off = 1; off < 256; off <<= 1){
    int v = (t >= off) ? part[t-off] : 0;
    __syncthreads();
    part[t] += v;
    __syncthreads();
  }
  int run = (t == 0) ? 0 : part[t-1];
  for (int i = 0; i < 40; ++i){
    int idx = base+i;
    if (idx < NN){ rowptr[idx] = run; cursor[idx] = run; run += deg[idx]; }
  }
  if (t == 255) rowptr[NN] = part[255];
}

__global__ void k_fill(const int* __restrict__ ei, int* __restrict__ cursor, int* __restrict__ csr_e){
  int e = blockIdx.x*256 + threadIdx.x;
  if (e >= NE) return;
  int s = ei[e];
  int pos = atomicAdd(&cursor[s], 1);
  csr_e[pos] = e;
}

// message pass, CSR by src: one wave per node; P2 row in registers; loop out-edges.
__global__ __launch_bounds__(256) void k_msg2(const int* __restrict__ rowptr, const int* __restrict__ csr_e,
                       const int* __restrict__ ei, const u32* __restrict__ e1u,
                       const u32* __restrict__ P2, const float* __restrict__ hb,
                       float* __restrict__ m){
  int t = threadIdx.x; int w = t >> 6; int o = t & 63;
  int n = blockIdx.x*4 + w;
  int jb = rowptr[n], je = rowptr[n+1];
  if (jb == je) return;
  float hbv = hb[n*64 + o];
  const u32* Pn = P2 + (size_t)n*2048;
  u32 pr[32];
  #pragma unroll
  for (int k2 = 0; k2 < 32; ++k2) pr[k2] = Pn[k2*64 + o];
  for (int j = jb; j < je; ++j){
    int e = csr_e[j];
    int dst = ei[NE + e];
    const u32* er = e1u + e*32;
    float acc = hbv;
    #pragma unroll 8
    for (int k2 = 0; k2 < 32; ++k2){
      u32 ew = er[k2];
      u32 pv = pr[k2];
      acc = fmaf(bf2f(ew & 0xffffu), bf2f(pv & 0xffffu), acc);
      acc = fmaf(bf2f(ew >> 16),     bf2f(pv >> 16),     acc);
    }
    atomicAdd(&m[dst*64 + o], acc);
  }
}

// GRU: one wave per node; also emits bf16 hi/lo split of new h
__global__ __launch_bounds__(256) void k_gru(const float* __restrict__ m, float* __restrict__ h,
                     unsigned short* __restrict__ hHi, unsigned short* __restrict__ hLo,
                     const float* __restrict__ wihT, const float* __restrict__ whhT,
                     const float* __restrict__ bih, const float* __restrict__ bhh){
  __shared__ float sm[4][64], sh[4][64];
  int t = threadIdx.x, w = t>>6, lane = t&63;
  int n = blockIdx.x*4 + w;
  sm[w][lane] = m[n*64+lane];
  sh[w][lane] = h[n*64+lane];
  __syncthreads();
  float gi0=0,gi1=0,gi2=0,gh0=0,gh1=0,gh2=0;
  #pragma unroll 2
  for (int i=0;i<64;++i){
    float mi = sm[w][i], hi = sh[w][i];
    const float* wr = wihT + i*192;
    const float* ur = whhT + i*192;
    gi0=fmaf(mi, wr[lane],     gi0);
    gi1=fmaf(mi, wr[64+lane],  gi1);
    gi2=fmaf(mi, wr[128+lane], gi2);
    gh0=fmaf(hi, ur[lane],     gh0);
    gh1=fmaf(hi, ur[64+lane],  gh1);
    gh2=fmaf(hi, ur[128+lane], gh2);
  }
  float r  = sigm(gi0+bih[lane]     + gh0+bhh[lane]);
  float z  = sigm(gi1+bih[64+lane]  + gh1+bhh[64+lane]);
  float nn_= tanhf(gi2+bih[128+lane] + r*(gh2+bhh[128+lane]));
  float ho = sh[w][lane];
  float hv = (1.f-z)*nn_ + z*ho;
  h[n*64+lane] = hv;
  u32 hv16 = f2bf(hv);
  hHi[n*64+lane] = (unsigned short)hv16;
  hLo[n*64+lane] = (unsigned short)f2bf(hv - bf2f(hv16));
}

// h2 = cat(h, x) @ lin_w^T + lin_b
__global__ __launch_bounds__(256) void k_lin(const float* __restrict__ h, const float* __restrict__ x,
                     const float* __restrict__ linT, const float* __restrict__ lin_b, float* __restrict__ h2){
  __shared__ float sh[4][64];
  int t=threadIdx.x, w=t>>6, lane=t&63;
  int n = blockIdx.x*4 + w;
  sh[w][lane] = h[n*64+lane];
  __syncthreads();
  float a0 = lin_b[lane], a1 = lin_b[64+lane];
  #pragma unroll 4
  for (int i=0;i<64;++i){
    float v = sh[w][i];
    a0 = fmaf(v, linT[i*128+lane], a0);
    a1 = fmaf(v, linT[i*128+64+lane], a1);
  }
  #pragma unroll
  for (int i=0;i<11;++i){
    float v = x[n*NNF+i];
    a0 = fmaf(v, linT[(64+i)*128+lane], a0);
    a1 = fmaf(v, linT[(64+i)*128+64+lane], a1);
  }
  h2[n*128+lane] = a0;
  h2[n*128+64+lane] = a1;
}

// graph ranges via binary search on sorted batch
__global__ void k_bounds(const int* __restrict__ batch, int* __restrict__ gstart){
  int b = blockIdx.x*256 + threadIdx.x;
  if (b > BG) return;
  int lo=0, hi=NN;
  while (lo < hi){ int mid=(lo+hi)>>1; if (batch[mid] < b) lo=mid+1; else hi=mid; }
  gstart[b]=lo;
}

// fused LSTM layer: block = one graph (512 threads); full-unrolled gate GEMV + activation.
template<int D1>
__global__ __launch_bounds__(512) void k_lstm(const float* __restrict__ in1, const float* __restrict__ w1T,
                     const float* __restrict__ in2, const float* __restrict__ w2T,
                     const float* __restrict__ bih, const float* __restrict__ bhh,
                     float* __restrict__ hS, float* __restrict__ cS){
  __shared__ float sg[512];
  int b = blockIdx.x, j = threadIdx.x;
  float a0 = bih[j] + bhh[j], a1 = 0.f, a2 = 0.f, a3 = 0.f;
  const float* i1 = in1 + b*D1;
  #pragma unroll
  for (int i = 0; i < D1; i += 4){
    a0 = fmaf(i1[i],   w1T[(i)*512+j],   a0);
    a1 = fmaf(i1[i+1], w1T[(i+1)*512+j], a1);
    a2 = fmaf(i1[i+2], w1T[(i+2)*512+j], a2);
    a3 = fmaf(i1[i+3], w1T[(i+3)*512+j], a3);
  }
  const float* i2 = in2 + b*128;
  #pragma unroll
  for (int i = 0; i < 128; i += 4){
    a0 = fmaf(i2[i],   w2T[(i)*512+j],   a0);
    a1 = fmaf(i2[i+1], w2T[(i+1)*512+j], a1);
    a2 = fmaf(i2[i+2], w2T[(i+2)*512+j], a2);
    a3 = fmaf(i2[i+3], w2T[(i+3)*512+j], a3);
  }
  sg[j] = (a0+a1)+(a2+a3);
  __syncthreads();
  if (j < 128){
    float ig = sigm(sg[j]), fg = sigm(sg[128+j]), gg = tanhf(sg[256+j]), og = sigm(sg[384+j]);
    int idx = b*128 + j;
    float c = fg*cS[idx] + ig*gg;
    cS[idx] = c;
    hS[idx] = og*tanhf(c);
  }
}

// per-graph online-softmax attention readout
__global__ __launch_bounds__(256) void k_attn(const float* __restrict__ h2, const float* __restrict__ h1s,
                       const int* __restrict__ gstart, float* __restrict__ qstar){
  int t=threadIdx.x, w=t>>6, lane=t&63;
  int b = blockIdx.x*4 + w;
  float q0 = h1s[b*128+lane], q1 = h1s[b*128+64+lane];
  int s = gstart[b], epos = gstart[b+1];
  float mrun = -3.0e38f, l = 0.f, r0=0.f, r1=0.f;
  for (int n=s; n<epos; ++n){
    float v0 = h2[n*128+lane], v1 = h2[n*128+64+lane];
    float d = fmaf(v0, q0, v1*q1);
    #pragma unroll
    for (int off=32; off; off>>=1) d += __shfl_xor(d, off);
    float mn = fmaxf(mrun, d);
    float sc = __expf(mrun - mn);
    float ww = __expf(d - mn);
    l = l*sc + ww;
    r0 = r0*sc + ww*v0;
    r1 = r1*sc + ww*v1;
    mrun = mn;
  }
  float inv = (l > 0.f) ? 1.f/l : 0.f;
  qstar[b*256 + lane]       = q0;
  qstar[b*256 + 64 + lane]  = q1;
  qstar[b*256 + 128 + lane] = r0*inv;
  qstar[b*256 + 192 + lane] = r1*inv;
}

// mid = relu(qstar @ w2a^T + b2a): block = one graph, full unroll
__global__ __launch_bounds__(512) void k_mid(const float* __restrict__ qstar, const float* __restrict__ w2aT,
                      const float* __restrict__ b2a, float* __restrict__ midb){
  int b = blockIdx.x, j = threadIdx.x;
  float a0 = b2a[j], a1 = 0.f, a2 = 0.f, a3 = 0.f;
  const float* q = qstar + b*256;
  #pragma unroll
  for (int i = 0; i < 256; i += 4){
    a0 = fmaf(q[i],   w2aT[(i)*512+j],   a0);
    a1 = fmaf(q[i+1], w2aT[(i+1)*512+j], a1);
    a2 = fmaf(q[i+2], w2aT[(i+2)*512+j], a2);
    a3 = fmaf(q[i+3], w2aT[(i+3)*512+j], a3);
  }
  midb[b*512 + j] = fmaxf((a0+a1)+(a2+a3), 0.f);
}

// out: one wave per (b,j) output; 8 elems/lane + shuffle reduce
__global__ __launch_bounds__(256) void k_out(const float* __restrict__ midb, const float* __restrict__ w2b,
                      const float* __restrict__ b2b, float* __restrict__ out){
  int t = threadIdx.x, w = t>>6, lane = t&63;
  int idx = blockIdx.x*4 + w;
  if (idx >= BG*NT) return;
  int b = idx / NT, j = idx - b*NT;
  const float* mb = midb + b*512;
  const float* wr = w2b + j*512;
  float acc = 0.f;
  #pragma unroll
  for (int i = 0; i < 8; ++i)
    acc = fmaf(mb[lane + i*64], wr[lane + i*64], acc);
  #pragma unroll
  for (int off=32; off; off>>=1) acc += __shfl_xor(acc, off);
  if (lane == 0) out[idx] = acc + b2b[j];
}

extern "C" void kernel_launch(void* const* d_in, const int* in_sizes, int n_in,
                              void* d_out, int out_size, void* d_ws, size_t ws_size,
                              hipStream_t stream) {
  const float* x    = (const float*)d_in[0];
  const float* ea   = (const float*)d_in[1];
  const int*   eidx = (const int*)d_in[2];
  const int*   batch= (const int*)d_in[3];
  const float* w1a  = (const float*)d_in[5];
  const float* b1a  = (const float*)d_in[6];
  const float* w1b  = (const float*)d_in[7];
  const float* b1b  = (const float*)d_in[8];
  const float* w1c  = (const float*)d_in[9];
  const float* b1c  = (const float*)d_in[10];
  const float* gwih = (const float*)d_in[11];
  const float* gwhh = (const float*)d_in[12];
  const float* gbih = (const float*)d_in[13];
  const float* gbhh = (const float*)d_in[14];
  const float* linw = (const float*)d_in[15];
  const float* linb = (const float*)d_in[16];
  const float* wih0 = (const float*)d_in[17];
  const float* whh0 = (const float*)d_in[18];
  const float* bih0 = (const float*)d_in[19];
  const float* bhh0 = (const float*)d_in[20];
  const float* wih1 = (const float*)d_in[21];
  const float* whh1 = (const float*)d_in[22];
  const float* bih1 = (const float*)d_in[23];
  const float* bhh1 = (const float*)d_in[24];
  const float* w2a  = (const float*)d_in[25];
  const float* b2a  = (const float*)d_in[26];
  const float* w2b  = (const float*)d_in[27];
  const float* b2b  = (const float*)d_in[28];
  float* out = (float*)d_out;

  char* p = (char*)d_ws;
  auto alloc = [&](size_t nbytes){ void* r = (void*)p; p += (nbytes + 255) & ~size_t(255); return r; };
  float* h    = (float*)alloc((size_t)NN*64*4);
  float* hb   = (float*)alloc((size_t)NN*64*4);
  float* m    = (float*)alloc((size_t)NN*64*4);
  float* h2   = (float*)alloc((size_t)NN*128*4);
  float* wihT = (float*)alloc(64*192*4);
  float* whhT = (float*)alloc(64*192*4);
  float* linT = (float*)alloc(75*128*4);
  float* w1bT = (float*)alloc(64*64*4);
  float* wih0T= (float*)alloc(256*512*4);
  float* whh0T= (float*)alloc(128*512*4);
  float* wih1T= (float*)alloc(128*512*4);
  float* whh1T= (float*)alloc(128*512*4);
  float* w2aT = (float*)alloc(256*512*4);
  float* qstar= (float*)alloc(256*256*4);
  float* h0   = (float*)alloc(256*128*4);
  float* c0   = (float*)alloc(256*128*4);
  float* h1s  = (float*)alloc(256*128*4);
  float* c1   = (float*)alloc(256*128*4);
  float* midb = (float*)alloc(256*512*4);
  int*  gstart= (int*)alloc(257*4);
  unsigned short* e1b = (unsigned short*)alloc((size_t)NE*64*2);
  unsigned short* qtT = (unsigned short*)alloc((size_t)4096*64*2);
  unsigned short* hHi = (unsigned short*)alloc((size_t)NN*64*2);
  unsigned short* hLo = (unsigned short*)alloc((size_t)NN*64*2);
  int*  deg   = (int*)alloc((size_t)NN*4);
  int*  rowptr= (int*)alloc((size_t)(NN+1)*4);
  int*  cursor= (int*)alloc((size_t)NN*4);
  int*  csr_e = (int*)alloc((size_t)NE*4);
  u32*  P2    = (u32*)alloc((size_t)NN*2048*4);

  k_h_init<<<2500, 256, 0, stream>>>(x, h, hHi, hLo);
  k_T<<<48, 256, 0, stream>>>(gwih, wihT, 192, 64);
  k_T<<<48, 256, 0, stream>>>(gwhh, whhT, 192, 64);
  k_T<<<38, 256, 0, stream>>>(linw, linT, 128, 75);
  k_T<<<16, 256, 0, stream>>>(w1b, w1bT, 64, 64);
  k_T<<<512, 256, 0, stream>>>(wih0, wih0T, 512, 256);
  k_T<<<256, 256, 0, stream>>>(whh0, whh0T, 512, 128);
  k_T<<<256, 256, 0, stream>>>(wih1, wih1T, 512, 128);
  k_T<<<256, 256, 0, stream>>>(whh1, whh1T, 512, 128);
  k_T<<<512, 256, 0, stream>>>(w2a, w2aT, 512, 256);
  k_qtt<<<1024, 256, 0, stream>>>(w1c, qtT);
  k_e1<<<12500, 256, 0, stream>>>(ea, w1a, b1a, w1bT, b1b, e1b);
  k_bounds<<<2, 256, 0, stream>>>(batch, gstart);
  hipMemsetAsync(qstar, 0, (256*256 + 4*256*128)*4, stream);

  // CSR by src (rebuilt every call; ws is re-poisoned)
  hipMemsetAsync(deg, 0, (size_t)NN*4, stream);
  k_deg<<<196, 256, 0, stream>>>(eidx, deg);
  k_scan<<<1, 256, 0, stream>>>(deg, rowptr, cursor);
  k_fill<<<196, 256, 0, stream>>>(eidx, cursor, csr_e);

  for (int t = 0; t < 3; ++t) {
    k_hb<<<2500, 256, 0, stream>>>(h, b1c, hb);
    k_P2<<<157*16, 256, 0, stream>>>(hHi, hLo, qtT, P2);
    hipMemsetAsync(m, 0, (size_t)NN*64*4, stream);
    k_msg2<<<2500, 256, 0, stream>>>(rowptr, csr_e, eidx, (const u32*)e1b, P2, hb, m);
    k_gru<<<2500, 256, 0, stream>>>(m, h, hHi, hLo, wihT, whhT, gbih, gbhh);
  }

  k_lin<<<2500, 256, 0, stream>>>(h, x, linT, linb, h2);

  for (int s = 0; s < 3; ++s) {
    k_lstm<256><<<256, 512, 0, stream>>>(qstar, wih0T, h0, whh0T, bih0, bhh0, h0, c0);
    k_lstm<128><<<256, 512, 0, stream>>>(h0, wih1T, h1s, whh1T, bih1, bhh1, h1s, c1);
    k_attn<<<64, 256, 0, stream>>>(h2, h1s, gstart, qstar);
  }

  k_mid<<<256, 512, 0, stream>>>(qstar, w2aT, b2a, midb);
  k_out<<<768, 256, 0, stream>>>(midb, w2b, b2b, out);
}